// Round 3
// baseline (80200.568 us; speedup 1.0000x reference)
//
#include <hip/hip_runtime.h>
#include <math.h>

#define TSTEPS 1024
#define HID    2048
#define IN_D   128
#define OUT_D  128
#define NWG    256
#define NTHR   512
#define FLAG_STRIDE 32   // uints -> 128B per flag slot

#define LOG2PI_F 1.8378770664093453f

static __device__ __forceinline__ float sigmoidf_(float x) {
    return 1.0f / (1.0f + expf(-x));
}

// ---------------------------------------------------------------------------
// Persistent LSTM rollout kernel.
// Grid: 256 WGs x 512 threads. WG w owns h-indices [8w, 8w+8) and the 32 gate
// rows {g*2048 + 8w + i : g in 0..3, i in 0..7}. W_hh is register-resident
// (f32, 128/thread). h propagates through a global double buffer.
// Grid barrier: distributed per-WG epoch flags (128B apart) + read-only
// polling (threads 0..255 each poll one flag) — no contended RMW.
// ---------------------------------------------------------------------------
__global__ __launch_bounds__(NTHR, 2)
void lstm_persist(const float* __restrict__ s0,
                  const float* __restrict__ Wih,
                  const float* __restrict__ Whh,
                  const float* __restrict__ bih,
                  const float* __restrict__ bhh,
                  float* __restrict__ hs_out,
                  unsigned int* __restrict__ flags,
                  float* __restrict__ hbuf0,
                  float* __restrict__ hbuf1)
{
    __shared__ __align__(16) float ldsH[HID];          // staged h (swizzled)
    __shared__ __align__(16) float ldsWih[32 * IN_D];  // W_ih slice
    __shared__ __align__(16) float ldsX[2][IN_D];      // x double buffer
    __shared__ __align__(16) float partial[8][33];     // [octet][li], padded
    __shared__ __align__(16) float partial2[16][33];   // [seg][li], padded
    __shared__ float gsum[32];
    __shared__ float biasLds[32];

    const int tid   = threadIdx.x;
    const int wg    = blockIdx.x;
    const int hbase = wg * 8;
    const int rg    = tid >> 6;   // wave id 0..7
    const int lane  = tid & 63;

    // ---- init: W_ih slice + bias + x0 into LDS ----
    {
        const int row = tid >> 4;           // 0..31 (local gate row li)
        const int seg = tid & 15;           // 8 floats each
        const int grow = (row >> 3) * HID + hbase + (row & 7);
        const float4* src = (const float4*)(Wih + (size_t)grow * IN_D + seg * 8);
        float4 a = src[0], b = src[1];
        float4* dst = (float4*)(&ldsWih[row * IN_D + seg * 8]);
        dst[0] = a; dst[1] = b;
    }
    if (tid < 32) {
        const int grow = (tid >> 3) * HID + hbase + (tid & 7);
        biasLds[tid] = bih[grow] + bhh[grow];
        float4 x = ((const float4*)s0)[tid];
        ((float4*)&ldsX[0][0])[tid] = x;
    }

    // ---- W_hh -> registers/AGPRs (f32, full precision) ----
    float w[4][32];
#pragma unroll
    for (int m = 0; m < 4; ++m) {
        const int li = rg * 4 + m;
        const int grow = (li >> 3) * HID + hbase + (li & 7);
        const float4* src = (const float4*)(Whh + (size_t)grow * HID + lane * 32);
#pragma unroll
        for (int q = 0; q < 8; ++q) {
            float4 v = src[q];
            w[m][4*q+0] = v.x; w[m][4*q+1] = v.y;
            w[m][4*q+2] = v.z; w[m][4*q+3] = v.w;
        }
    }

    float c_reg = 0.0f;
    __syncthreads();

    for (int t = 0; t < TSTEPS; ++t) {
        const int cur = t & 1;
        const float* hb_cur = cur ? hbuf1 : hbuf0;
        float*       hb_nxt = cur ? hbuf0 : hbuf1;

        // ---- stage h into LDS, XOR-swizzled (16B chunk p = c ^ ((c>>3)&7)) ----
        {
            float4 hv = ((const float4*)hb_cur)[tid];
            const int p = tid ^ ((tid >> 3) & 7);
            ((float4*)ldsH)[p] = hv;
        }
        // prefetch next x (load early, LDS-write later)
        float4 xpre;
        const bool do_pre = (tid < 32) && (t + 1 < TSTEPS);
        if (do_pre) xpre = ((const float4*)(s0 + (size_t)(t + 1) * IN_D))[tid];
        __syncthreads();

        // ---- main recurrent matvec: 4 rows x 32 k per thread ----
        float acc[4] = {0.f, 0.f, 0.f, 0.f};
#pragma unroll
        for (int j = 0; j < 8; ++j) {
            const int c = 8 * lane + j;
            const int p = c ^ (lane & 7);
            float4 hv = ((const float4*)ldsH)[p];
#pragma unroll
            for (int m = 0; m < 4; ++m) {
                acc[m] += hv.x * w[m][4*j+0];
                acc[m] += hv.y * w[m][4*j+1];
                acc[m] += hv.z * w[m][4*j+2];
                acc[m] += hv.w * w[m][4*j+3];
            }
        }

        // ---- input-to-hidden partial (W_ih @ x_t), spread over all threads ----
        {
            const int row = tid >> 4;
            const int seg = tid & 15;
            const float* xv = &ldsX[cur][seg * 8];
            const float* wv = &ldsWih[row * IN_D + seg * 8];
            float p2 = 0.f;
#pragma unroll
            for (int q = 0; q < 8; ++q) p2 += xv[q] * wv[q];
            partial2[seg][row] = p2;
        }

        // ---- reduce main dot over k within wave (octets of 8 lanes) ----
#pragma unroll
        for (int m = 0; m < 4; ++m) {
            acc[m] += __shfl_xor(acc[m], 1);
            acc[m] += __shfl_xor(acc[m], 2);
            acc[m] += __shfl_xor(acc[m], 4);
        }
        if ((lane & 7) == 0) {
            *(float4*)&partial[lane >> 3][rg * 4] = make_float4(acc[0], acc[1], acc[2], acc[3]);
        }
        if (do_pre) ((float4*)&ldsX[cur ^ 1][0])[tid] = xpre;
        __syncthreads();

        // ---- stage 2: final gate sums ----
        if (tid < 32) {
            float g = biasLds[tid];
#pragma unroll
            for (int o = 0; o < 8; ++o) g += partial[o][tid];
#pragma unroll
            for (int sgi = 0; sgi < 16; ++sgi) g += partial2[sgi][tid];
            gsum[tid] = g;
        }
        __syncthreads();

        // ---- cell update (threads 0..7 own one h-index each) ----
        if (tid < 8) {
            const float zi = gsum[tid];
            const float zf = gsum[8 + tid];
            const float zg = gsum[16 + tid];
            const float zo = gsum[24 + tid];
            const float ig = sigmoidf_(zi);
            const float fg = sigmoidf_(zf);
            const float og = sigmoidf_(zo);
            const float gg = tanhf(zg);
            c_reg = fg * c_reg + ig * gg;
            const float h = og * tanhf(c_reg);
            hb_nxt[hbase + tid] = h;
            hs_out[(size_t)t * HID + hbase + tid] = h;
        }

        // ---- grid barrier: distributed flags, read-only polling ----
        __threadfence();          // release this WG's h writes
        __syncthreads();
        if (tid == 0) {
            __hip_atomic_store(&flags[wg * FLAG_STRIDE], (unsigned int)(t + 1),
                               __ATOMIC_RELEASE, __HIP_MEMORY_SCOPE_AGENT);
        }
        if (tid < NWG) {
            while (__hip_atomic_load(&flags[tid * FLAG_STRIDE],
                                     __ATOMIC_ACQUIRE, __HIP_MEMORY_SCOPE_AGENT)
                   < (unsigned int)(t + 1)) { /* spin */ }
        }
        __syncthreads();
        __threadfence();          // make all WGs' h writes visible to all lanes
    }
}

// ---------------------------------------------------------------------------
// Output head: mu/logvar GEMV + sample + logprob. Block = 4 timesteps,
// thread tid<128 -> mu row tid, tid>=128 -> lv row tid-128. hs is L2/L3-hot.
// ---------------------------------------------------------------------------
__global__ __launch_bounds__(256)
void out_head(const float* __restrict__ eps,
              const float* __restrict__ Wmu,
              const float* __restrict__ bmu,
              const float* __restrict__ Wlv,
              const float* __restrict__ blv,
              const float* __restrict__ hs,
              float* __restrict__ xs,
              float* __restrict__ lp)
{
    __shared__ __align__(16) float hlds[4][HID];
    __shared__ __align__(16) float exch[4][256];

    const int tid = threadIdx.x;
    const int t0  = blockIdx.x * 4;

    {
        const float4* src = (const float4*)(hs + (size_t)t0 * HID);
        float4* dst = (float4*)&hlds[0][0];
#pragma unroll
        for (int i = 0; i < 8; ++i)
            dst[tid + i * 256] = src[tid + i * 256];
    }
    __syncthreads();

    const int  jrow  = tid & 127;
    const bool is_lv = tid >= 128;
    const float* Wrow = (is_lv ? Wlv : Wmu) + (size_t)jrow * HID;
    const float  bias = is_lv ? blv[jrow] : bmu[jrow];

    float acc[4] = {0.f, 0.f, 0.f, 0.f};
    const float4* w4 = (const float4*)Wrow;
#pragma unroll 4
    for (int kq = 0; kq < HID / 4; ++kq) {
        float4 wv = w4[kq];
#pragma unroll
        for (int tt = 0; tt < 4; ++tt) {
            float4 hv = ((const float4*)&hlds[tt][0])[kq];
            acc[tt] += wv.x * hv.x + wv.y * hv.y + wv.z * hv.z + wv.w * hv.w;
        }
    }
#pragma unroll
    for (int tt = 0; tt < 4; ++tt) exch[tt][tid] = acc[tt] + bias;
    __syncthreads();

#pragma unroll
    for (int r = 0; r < 2; ++r) {
        const int item = tid + r * 256;
        const int tt = item >> 7;
        const int jj = item & 127;
        const int t  = t0 + tt;
        const float mu = exch[tt][jj];
        const float lv = exch[tt][128 + jj];
        const float e  = eps[(size_t)t * OUT_D + jj];
        const float sd = expf(0.5f * lv);
        const float x  = mu + sd * e;
        const float d  = (x - mu) / sd;
        const float l  = -0.5f * d * d - 0.5f * lv - 0.5f * LOG2PI_F;
        xs[(size_t)t * OUT_D + jj] = x;
        lp[(size_t)t * OUT_D + jj] = l;
    }
}

// ---------------------------------------------------------------------------
extern "C" void kernel_launch(void* const* d_in, const int* in_sizes, int n_in,
                              void* d_out, int out_size, void* d_ws, size_t ws_size,
                              hipStream_t stream)
{
    (void)in_sizes; (void)n_in; (void)out_size; (void)ws_size;

    const float* s0  = (const float*)d_in[0];
    const float* eps = (const float*)d_in[1];
    const float* Wih = (const float*)d_in[2];
    const float* Whh = (const float*)d_in[3];
    const float* bih = (const float*)d_in[4];
    const float* bhh = (const float*)d_in[5];
    const float* Wmu = (const float*)d_in[6];
    const float* bmu = (const float*)d_in[7];
    const float* Wlv = (const float*)d_in[8];
    const float* blv = (const float*)d_in[9];

    float* out = (float*)d_out;
    float* xs = out;                         // [1024][128]
    float* lp = out + TSTEPS * OUT_D;        // [1024][128]
    float* hs = out + 2 * TSTEPS * OUT_D;    // [1024][2048]

    unsigned int* flags = (unsigned int*)d_ws;                    // 256 x 128B = 32KB
    float* hbuf0 = (float*)((char*)d_ws + 32768);
    float* hbuf1 = (float*)((char*)d_ws + 32768 + HID * sizeof(float));

    // zero flags + both h buffers (h0 = 0)
    (void)hipMemsetAsync(d_ws, 0, 32768 + 2 * HID * sizeof(float), stream);

    hipLaunchKernelGGL(lstm_persist, dim3(NWG), dim3(NTHR), 0, stream,
                       s0, Wih, Whh, bih, bhh, hs, flags, hbuf0, hbuf1);

    hipLaunchKernelGGL(out_head, dim3(TSTEPS / 4), dim3(256), 0, stream,
                       eps, Wmu, bmu, Wlv, blv, hs, xs, lp);
}

// Round 4
// 3945.317 us; speedup vs baseline: 20.3280x; 20.3280x over previous
//
#include <hip/hip_runtime.h>
#include <math.h>

#define TSTEPS 1024
#define HID    2048
#define IN_D   128
#define OUT_D  128
#define NWG    256
#define NTHR   512
#define FLAG_STRIDE 32   // uints -> 128B per flag slot

#define LOG2PI_F 1.8378770664093453f

static __device__ __forceinline__ float sigmoidf_(float x) {
    return 1.0f / (1.0f + expf(-x));
}

// ---------------------------------------------------------------------------
// Persistent LSTM rollout kernel.
// Grid: 256 WGs x 512 threads. WG w owns h-indices [8w, 8w+8) and the 32 gate
// rows {g*2048 + 8w + i : g in 0..3, i in 0..7}. W_hh is register-resident
// (f32, 128/thread). ALL cross-WG traffic (h, flags, done) uses RELAXED
// agent-scope atomics (plain sc1 accesses served by the coherent L3) — no
// threadfence / release / acquire, so no buffer_wbl2 / buffer_inv storms.
// Producer ordering: s_waitcnt vmcnt(0) between h stores and flag store.
// Barrier: two-level, one writer + one poller per cache line, s_sleep backoff.
// ---------------------------------------------------------------------------
__global__ __launch_bounds__(NTHR, 2)
void lstm_persist(const float* __restrict__ s0,
                  const float* __restrict__ Wih,
                  const float* __restrict__ Whh,
                  const float* __restrict__ bih,
                  const float* __restrict__ bhh,
                  float* __restrict__ hs_out,
                  unsigned int* __restrict__ flags,   // [NWG] stride 32
                  unsigned int* __restrict__ done,    // [NWG] stride 32
                  float* __restrict__ hbuf0,
                  float* __restrict__ hbuf1)
{
    __shared__ __align__(16) float ldsH[HID];          // staged h (swizzled)
    __shared__ __align__(16) float ldsWih[32 * IN_D];  // W_ih slice
    __shared__ __align__(16) float ldsX[2][IN_D];      // x double buffer
    __shared__ __align__(16) float partial[8][33];     // [octet][li], padded
    __shared__ __align__(16) float partial2[16][33];   // [seg][li], padded
    __shared__ float gsum[32];
    __shared__ float biasLds[32];

    const int tid   = threadIdx.x;
    const int wg    = blockIdx.x;
    const int hbase = wg * 8;
    const int rg    = tid >> 6;   // wave id 0..7
    const int lane  = tid & 63;

    // ---- init: W_ih slice + bias + x0 into LDS ----
    {
        const int row = tid >> 4;           // 0..31 (local gate row li)
        const int seg = tid & 15;           // 8 floats each
        const int grow = (row >> 3) * HID + hbase + (row & 7);
        const float4* src = (const float4*)(Wih + (size_t)grow * IN_D + seg * 8);
        float4 a = src[0], b = src[1];
        float4* dst = (float4*)(&ldsWih[row * IN_D + seg * 8]);
        dst[0] = a; dst[1] = b;
    }
    if (tid < 32) {
        const int grow = (tid >> 3) * HID + hbase + (tid & 7);
        biasLds[tid] = bih[grow] + bhh[grow];
        float4 x = ((const float4*)s0)[tid];
        ((float4*)&ldsX[0][0])[tid] = x;
    }

    // ---- W_hh -> registers/AGPRs (f32, full precision) ----
    float w[4][32];
#pragma unroll
    for (int m = 0; m < 4; ++m) {
        const int li = rg * 4 + m;
        const int grow = (li >> 3) * HID + hbase + (li & 7);
        const float4* src = (const float4*)(Whh + (size_t)grow * HID + lane * 32);
#pragma unroll
        for (int q = 0; q < 8; ++q) {
            float4 v = src[q];
            w[m][4*q+0] = v.x; w[m][4*q+1] = v.y;
            w[m][4*q+2] = v.z; w[m][4*q+3] = v.w;
        }
    }

    float c_reg = 0.0f;
    __syncthreads();

    for (int t = 0; t < TSTEPS; ++t) {
        const int cur = t & 1;
        const float* hb_cur = cur ? hbuf1 : hbuf0;
        float*       hb_nxt = cur ? hbuf0 : hbuf1;

        // ---- stage h into LDS via relaxed sc1 loads (L3-fresh), swizzled ----
        {
            float4 hv;
            hv.x = __hip_atomic_load(&hb_cur[4*tid+0], __ATOMIC_RELAXED, __HIP_MEMORY_SCOPE_AGENT);
            hv.y = __hip_atomic_load(&hb_cur[4*tid+1], __ATOMIC_RELAXED, __HIP_MEMORY_SCOPE_AGENT);
            hv.z = __hip_atomic_load(&hb_cur[4*tid+2], __ATOMIC_RELAXED, __HIP_MEMORY_SCOPE_AGENT);
            hv.w = __hip_atomic_load(&hb_cur[4*tid+3], __ATOMIC_RELAXED, __HIP_MEMORY_SCOPE_AGENT);
            const int p = tid ^ ((tid >> 3) & 7);
            ((float4*)ldsH)[p] = hv;
        }
        // prefetch next x (load early, LDS-write later)
        float4 xpre;
        const bool do_pre = (tid < 32) && (t + 1 < TSTEPS);
        if (do_pre) xpre = ((const float4*)(s0 + (size_t)(t + 1) * IN_D))[tid];
        __syncthreads();

        // ---- main recurrent matvec: 4 rows x 32 k per thread ----
        float acc[4] = {0.f, 0.f, 0.f, 0.f};
#pragma unroll
        for (int j = 0; j < 8; ++j) {
            const int c = 8 * lane + j;
            const int p = c ^ (lane & 7);
            float4 hv = ((const float4*)ldsH)[p];
#pragma unroll
            for (int m = 0; m < 4; ++m) {
                acc[m] += hv.x * w[m][4*j+0];
                acc[m] += hv.y * w[m][4*j+1];
                acc[m] += hv.z * w[m][4*j+2];
                acc[m] += hv.w * w[m][4*j+3];
            }
        }

        // ---- input-to-hidden partial (W_ih @ x_t), spread over all threads ----
        {
            const int row = tid >> 4;
            const int seg = tid & 15;
            const float* xv = &ldsX[cur][seg * 8];
            const float* wv = &ldsWih[row * IN_D + seg * 8];
            float p2 = 0.f;
#pragma unroll
            for (int q = 0; q < 8; ++q) p2 += xv[q] * wv[q];
            partial2[seg][row] = p2;
        }

        // ---- reduce main dot over k within wave (octets of 8 lanes) ----
#pragma unroll
        for (int m = 0; m < 4; ++m) {
            acc[m] += __shfl_xor(acc[m], 1);
            acc[m] += __shfl_xor(acc[m], 2);
            acc[m] += __shfl_xor(acc[m], 4);
        }
        if ((lane & 7) == 0) {
            *(float4*)&partial[lane >> 3][rg * 4] = make_float4(acc[0], acc[1], acc[2], acc[3]);
        }
        if (do_pre) ((float4*)&ldsX[cur ^ 1][0])[tid] = xpre;
        __syncthreads();

        // ---- stage 2: final gate sums ----
        if (tid < 32) {
            float g = biasLds[tid];
#pragma unroll
            for (int o = 0; o < 8; ++o) g += partial[o][tid];
#pragma unroll
            for (int sgi = 0; sgi < 16; ++sgi) g += partial2[sgi][tid];
            gsum[tid] = g;
        }
        __syncthreads();

        // ---- cell update (threads 0..7 own one h-index each) ----
        if (tid < 8) {
            const float zi = gsum[tid];
            const float zf = gsum[8 + tid];
            const float zg = gsum[16 + tid];
            const float zo = gsum[24 + tid];
            const float ig = sigmoidf_(zi);
            const float fg = sigmoidf_(zf);
            const float og = sigmoidf_(zo);
            const float gg = tanhf(zg);
            c_reg = fg * c_reg + ig * gg;
            const float h = og * tanhf(c_reg);
            // h -> L3 directly (sc1, no L2 dirtiness, no fence needed later)
            __hip_atomic_store(&hb_nxt[hbase + tid], h, __ATOMIC_RELAXED, __HIP_MEMORY_SCOPE_AGENT);
            hs_out[(size_t)t * HID + hbase + tid] = h;
        }

        // wave-local drain: h stores are complete (visible at L3) past here
        asm volatile("s_waitcnt vmcnt(0)" ::: "memory");
        __syncthreads();

        if (tid == 0) {
            __hip_atomic_store(&flags[wg * FLAG_STRIDE], (unsigned int)(t + 1),
                               __ATOMIC_RELAXED, __HIP_MEMORY_SCOPE_AGENT);
        }

        // ---- two-level barrier: WG0 gathers flags, fans out per-WG done ----
        if (wg == 0) {
            if (tid < NWG) {
                while (__hip_atomic_load(&flags[tid * FLAG_STRIDE],
                                         __ATOMIC_RELAXED, __HIP_MEMORY_SCOPE_AGENT)
                       < (unsigned int)(t + 1))
                    __builtin_amdgcn_s_sleep(1);
            }
            __syncthreads();
            if (tid < NWG) {
                __hip_atomic_store(&done[tid * FLAG_STRIDE], (unsigned int)(t + 1),
                                   __ATOMIC_RELAXED, __HIP_MEMORY_SCOPE_AGENT);
            }
        } else {
            if (tid == 0) {
                while (__hip_atomic_load(&done[wg * FLAG_STRIDE],
                                         __ATOMIC_RELAXED, __HIP_MEMORY_SCOPE_AGENT)
                       < (unsigned int)(t + 1))
                    __builtin_amdgcn_s_sleep(1);
            }
            __syncthreads();
        }
        // next-iteration h loads are sc1 (L3-direct) and issued after the
        // barrier -> they observe all producers' h stores. No cache inv needed.
    }
}

// ---------------------------------------------------------------------------
// Output head: mu/logvar GEMV + sample + logprob. Block = 4 timesteps,
// thread tid<128 -> mu row tid, tid>=128 -> lv row tid-128. hs is L2/L3-hot.
// ---------------------------------------------------------------------------
__global__ __launch_bounds__(256)
void out_head(const float* __restrict__ eps,
              const float* __restrict__ Wmu,
              const float* __restrict__ bmu,
              const float* __restrict__ Wlv,
              const float* __restrict__ blv,
              const float* __restrict__ hs,
              float* __restrict__ xs,
              float* __restrict__ lp)
{
    __shared__ __align__(16) float hlds[4][HID];
    __shared__ __align__(16) float exch[4][256];

    const int tid = threadIdx.x;
    const int t0  = blockIdx.x * 4;

    {
        const float4* src = (const float4*)(hs + (size_t)t0 * HID);
        float4* dst = (float4*)&hlds[0][0];
#pragma unroll
        for (int i = 0; i < 8; ++i)
            dst[tid + i * 256] = src[tid + i * 256];
    }
    __syncthreads();

    const int  jrow  = tid & 127;
    const bool is_lv = tid >= 128;
    const float* Wrow = (is_lv ? Wlv : Wmu) + (size_t)jrow * HID;
    const float  bias = is_lv ? blv[jrow] : bmu[jrow];

    float acc[4] = {0.f, 0.f, 0.f, 0.f};
    const float4* w4 = (const float4*)Wrow;
#pragma unroll 4
    for (int kq = 0; kq < HID / 4; ++kq) {
        float4 wv = w4[kq];
#pragma unroll
        for (int tt = 0; tt < 4; ++tt) {
            float4 hv = ((const float4*)&hlds[tt][0])[kq];
            acc[tt] += wv.x * hv.x + wv.y * hv.y + wv.z * hv.z + wv.w * hv.w;
        }
    }
#pragma unroll
    for (int tt = 0; tt < 4; ++tt) exch[tt][tid] = acc[tt] + bias;
    __syncthreads();

#pragma unroll
    for (int r = 0; r < 2; ++r) {
        const int item = tid + r * 256;
        const int tt = item >> 7;
        const int jj = item & 127;
        const int t  = t0 + tt;
        const float mu = exch[tt][jj];
        const float lv = exch[tt][128 + jj];
        const float e  = eps[(size_t)t * OUT_D + jj];
        const float sd = expf(0.5f * lv);
        const float x  = mu + sd * e;
        const float d  = (x - mu) / sd;
        const float l  = -0.5f * d * d - 0.5f * lv - 0.5f * LOG2PI_F;
        xs[(size_t)t * OUT_D + jj] = x;
        lp[(size_t)t * OUT_D + jj] = l;
    }
}

// ---------------------------------------------------------------------------
extern "C" void kernel_launch(void* const* d_in, const int* in_sizes, int n_in,
                              void* d_out, int out_size, void* d_ws, size_t ws_size,
                              hipStream_t stream)
{
    (void)in_sizes; (void)n_in; (void)out_size; (void)ws_size;

    const float* s0  = (const float*)d_in[0];
    const float* eps = (const float*)d_in[1];
    const float* Wih = (const float*)d_in[2];
    const float* Whh = (const float*)d_in[3];
    const float* bih = (const float*)d_in[4];
    const float* bhh = (const float*)d_in[5];
    const float* Wmu = (const float*)d_in[6];
    const float* bmu = (const float*)d_in[7];
    const float* Wlv = (const float*)d_in[8];
    const float* blv = (const float*)d_in[9];

    float* out = (float*)d_out;
    float* xs = out;                         // [1024][128]
    float* lp = out + TSTEPS * OUT_D;        // [1024][128]
    float* hs = out + 2 * TSTEPS * OUT_D;    // [1024][2048]

    unsigned int* flags = (unsigned int*)d_ws;                        // 32KB
    unsigned int* done  = (unsigned int*)((char*)d_ws + 32768);       // 32KB
    float* hbuf0 = (float*)((char*)d_ws + 65536);
    float* hbuf1 = (float*)((char*)d_ws + 65536 + HID * sizeof(float));

    // zero flags + done + both h buffers (h0 = 0)
    (void)hipMemsetAsync(d_ws, 0, 65536 + 2 * HID * sizeof(float), stream);

    hipLaunchKernelGGL(lstm_persist, dim3(NWG), dim3(NTHR), 0, stream,
                       s0, Wih, Whh, bih, bhh, hs, flags, done, hbuf0, hbuf1);

    hipLaunchKernelGGL(out_head, dim3(TSTEPS / 4), dim3(256), 0, stream,
                       eps, Wmu, bmu, Wlv, blv, hs, xs, lp);
}

// Round 5
// 3873.449 us; speedup vs baseline: 20.7052x; 1.0186x over previous
//
#include <hip/hip_runtime.h>
#include <math.h>

#define TSTEPS 1024
#define HID    2048
#define IN_D   128
#define OUT_D  128
#define NWG    256
#define NTHR   512
#define FLAG_STRIDE 32   // uints -> 128B per flag slot

#define LOG2PI_F 1.8378770664093453f

static __device__ __forceinline__ float sigmoidf_(float x) {
    return 1.0f / (1.0f + expf(-x));
}

// ---------------------------------------------------------------------------
// Persistent LSTM rollout. 256 WGs x 512 threads; WG w owns h[8w..8w+8) and
// gate rows {g*2048 + 8w + i}. W_hh register-resident (128 f32/thread).
// h transport: hs_out itself (unique slot per step -> no WAR, no barrier).
// Sync: per-producer epoch flags, relaxed agent-scope (sc1/L3) only.
//   producer: h sc1-stores -> s_waitcnt vmcnt(0) -> flag := t+1
//   consumer: poll flags[tid>>1] >= t -> load own 16B of h(t-1) -> LDS
// Per-step critical path ~= flag propagate + h load + matvec + butterfly.
// W_ih@x: 8 reg FMAs/thread folded into the same butterfly, computed before
// the poll (x double-buffered in LDS). No cross-octet LDS reduction stages.
// ---------------------------------------------------------------------------
__global__ __launch_bounds__(NTHR, 2)
void lstm_persist(const float* __restrict__ s0,
                  const float* __restrict__ Wih,
                  const float* __restrict__ Whh,
                  const float* __restrict__ bih,
                  const float* __restrict__ bhh,
                  float* __restrict__ hs_out,
                  unsigned int* __restrict__ flags)
{
    __shared__ __align__(16) float4 ldsH[2][HID / 4];  // staged h, swizzled, dbuf
    __shared__ __align__(16) float  ldsX[2][IN_D];     // x double buffer
    __shared__ __align__(16) float  gsum[32];

    const int tid   = threadIdx.x;
    const int wg    = blockIdx.x;
    const int hbase = wg * 8;
    const int rg    = tid >> 6;   // wave id 0..7
    const int lane  = tid & 63;

    // ---- W_hh -> registers: rows rg*4+m, k-slice [lane*32, lane*32+32) ----
    float w[4][32];
    int growm[4];
#pragma unroll
    for (int m = 0; m < 4; ++m) {
        const int li = rg * 4 + m;
        growm[m] = (li >> 3) * HID + hbase + (li & 7);
        const float4* src = (const float4*)(Whh + (size_t)growm[m] * HID + lane * 32);
#pragma unroll
        for (int q = 0; q < 8; ++q) {
            float4 v = src[q];
            w[m][4*q+0] = v.x; w[m][4*q+1] = v.y;
            w[m][4*q+2] = v.z; w[m][4*q+3] = v.w;
        }
    }
    // ---- W_ih -> registers: rows rg*4+m, k {2*lane, 2*lane+1} ----
    float wih2[4][2];
    float breg[4];
#pragma unroll
    for (int m = 0; m < 4; ++m) {
        wih2[m][0] = Wih[(size_t)growm[m] * IN_D + 2 * lane];
        wih2[m][1] = Wih[(size_t)growm[m] * IN_D + 2 * lane + 1];
        breg[m]    = bih[growm[m]] + bhh[growm[m]];
    }

    // ---- x0 into LDS ----
    if (tid < 32) ((float4*)&ldsX[0][0])[tid] = ((const float4*)s0)[tid];

    float c_reg = 0.0f;
    __syncthreads();

    for (int t = 0; t < TSTEPS; ++t) {
        const int cur = t & 1;

        // ---- W_ih @ x_t partial (no h dependency; before the poll) ----
        const float2 xv = *(const float2*)&ldsX[cur][2 * lane];
        float acc[4];
#pragma unroll
        for (int m = 0; m < 4; ++m)
            acc[m] = wih2[m][0] * xv.x + wih2[m][1] * xv.y;

        // ---- wait for own producer's h(t-1), load 16B, stage swizzled ----
        if (t > 0) {
            const unsigned int want = (unsigned int)t;
            while (__hip_atomic_load(&flags[(tid >> 1) * FLAG_STRIDE],
                                     __ATOMIC_RELAXED, __HIP_MEMORY_SCOPE_AGENT) < want)
                __builtin_amdgcn_s_sleep(1);
            asm volatile("" ::: "memory");   // no hoisting of h loads above poll
            const float* hsrc = hs_out + (size_t)(t - 1) * HID + 4 * tid;
            float4 hv;
            hv.x = __hip_atomic_load(hsrc + 0, __ATOMIC_RELAXED, __HIP_MEMORY_SCOPE_AGENT);
            hv.y = __hip_atomic_load(hsrc + 1, __ATOMIC_RELAXED, __HIP_MEMORY_SCOPE_AGENT);
            hv.z = __hip_atomic_load(hsrc + 2, __ATOMIC_RELAXED, __HIP_MEMORY_SCOPE_AGENT);
            hv.w = __hip_atomic_load(hsrc + 3, __ATOMIC_RELAXED, __HIP_MEMORY_SCOPE_AGENT);
            const int p = tid ^ ((tid >> 3) & 7);
            ldsH[cur][p] = hv;
        }
        // prefetch x_{t+1} into the other x buffer (pre-sync; read next iter)
        if (tid < 32 && t + 1 < TSTEPS) {
            float4 xp = ((const float4*)(s0 + (size_t)(t + 1) * IN_D))[tid];
            ((float4*)&ldsX[cur ^ 1][0])[tid] = xp;
        }
        __syncthreads();   // sync1: ldsH staged, ldsX[next] written

        // ---- recurrent matvec: 4 rows x 32 k per thread ----
        if (t > 0) {
#pragma unroll
            for (int j = 0; j < 8; ++j) {
                const int c4 = 8 * lane + j;
                const int p  = c4 ^ (lane & 7);
                float4 hv = ldsH[cur][p];
#pragma unroll
                for (int m = 0; m < 4; ++m) {
                    acc[m] += hv.x * w[m][4*j+0];
                    acc[m] += hv.y * w[m][4*j+1];
                    acc[m] += hv.z * w[m][4*j+2];
                    acc[m] += hv.w * w[m][4*j+3];
                }
            }
        }

        // ---- full 64-lane butterfly: complete gate preactivations at lane 0 ----
#pragma unroll
        for (int m = 0; m < 4; ++m) {
            acc[m] += __shfl_xor(acc[m], 1);
            acc[m] += __shfl_xor(acc[m], 2);
            acc[m] += __shfl_xor(acc[m], 4);
            acc[m] += __shfl_xor(acc[m], 8);
            acc[m] += __shfl_xor(acc[m], 16);
            acc[m] += __shfl_xor(acc[m], 32);
        }
        if (lane == 0) {
            *(float4*)&gsum[rg * 4] = make_float4(acc[0] + breg[0], acc[1] + breg[1],
                                                  acc[2] + breg[2], acc[3] + breg[3]);
        }
        __syncthreads();   // sync2: gsum ready

        // ---- cell update + h publish (wave 0) ----
        if (tid < 8) {
            const float zi = gsum[tid];
            const float zf = gsum[8 + tid];
            const float zg = gsum[16 + tid];
            const float zo = gsum[24 + tid];
            const float ig = sigmoidf_(zi);
            const float fg = sigmoidf_(zf);
            const float og = sigmoidf_(zo);
            const float gg = tanhf(zg);
            c_reg = fg * c_reg + ig * gg;
            const float h = og * tanhf(c_reg);
            // h -> L3 directly; doubles as the hs output
            __hip_atomic_store(&hs_out[(size_t)t * HID + hbase + tid], h,
                               __ATOMIC_RELAXED, __HIP_MEMORY_SCOPE_AGENT);
        }
        if (rg == 0) {
            // drain wave 0's h stores to the coherent point before flagging
            asm volatile("s_waitcnt vmcnt(0)" ::: "memory");
        }
        if (tid == 0) {
            __hip_atomic_store(&flags[wg * FLAG_STRIDE], (unsigned int)(t + 1),
                               __ATOMIC_RELAXED, __HIP_MEMORY_SCOPE_AGENT);
        }
        // no global barrier: skew is bounded by the flag/data dependence itself
    }
}

// ---------------------------------------------------------------------------
// Output head: mu/logvar GEMV + sample + logprob. Block = 4 timesteps.
// hs was written with sc1 (L2-bypassed) stores -> stage it with relaxed
// agent-scope loads (always L3-fresh, immune to stale L2 poison lines).
// ---------------------------------------------------------------------------
__global__ __launch_bounds__(256)
void out_head(const float* __restrict__ eps,
              const float* __restrict__ Wmu,
              const float* __restrict__ bmu,
              const float* __restrict__ Wlv,
              const float* __restrict__ blv,
              const float* __restrict__ hs,
              float* __restrict__ xs,
              float* __restrict__ lp)
{
    __shared__ __align__(16) float hlds[4][HID];
    __shared__ __align__(16) float exch[4][256];

    const int tid = threadIdx.x;
    const int t0  = blockIdx.x * 4;

    {
        const float* src = hs + (size_t)t0 * HID;
        float* dst = &hlds[0][0];
#pragma unroll
        for (int i = 0; i < 32; ++i)
            dst[tid + i * 256] = __hip_atomic_load(src + tid + i * 256,
                                                   __ATOMIC_RELAXED, __HIP_MEMORY_SCOPE_AGENT);
    }
    __syncthreads();

    const int  jrow  = tid & 127;
    const bool is_lv = tid >= 128;
    const float* Wrow = (is_lv ? Wlv : Wmu) + (size_t)jrow * HID;
    const float  bias = is_lv ? blv[jrow] : bmu[jrow];

    float acc[4] = {0.f, 0.f, 0.f, 0.f};
    const float4* w4 = (const float4*)Wrow;
#pragma unroll 4
    for (int kq = 0; kq < HID / 4; ++kq) {
        float4 wv = w4[kq];
#pragma unroll
        for (int tt = 0; tt < 4; ++tt) {
            float4 hv = ((const float4*)&hlds[tt][0])[kq];
            acc[tt] += wv.x * hv.x + wv.y * hv.y + wv.z * hv.z + wv.w * hv.w;
        }
    }
#pragma unroll
    for (int tt = 0; tt < 4; ++tt) exch[tt][tid] = acc[tt] + bias;
    __syncthreads();

#pragma unroll
    for (int r = 0; r < 2; ++r) {
        const int item = tid + r * 256;
        const int tt = item >> 7;
        const int jj = item & 127;
        const int t  = t0 + tt;
        const float mu = exch[tt][jj];
        const float lv = exch[tt][128 + jj];
        const float e  = eps[(size_t)t * OUT_D + jj];
        const float sd = expf(0.5f * lv);
        const float x  = mu + sd * e;
        const float d  = (x - mu) / sd;
        const float l  = -0.5f * d * d - 0.5f * lv - 0.5f * LOG2PI_F;
        xs[(size_t)t * OUT_D + jj] = x;
        lp[(size_t)t * OUT_D + jj] = l;
    }
}

// ---------------------------------------------------------------------------
extern "C" void kernel_launch(void* const* d_in, const int* in_sizes, int n_in,
                              void* d_out, int out_size, void* d_ws, size_t ws_size,
                              hipStream_t stream)
{
    (void)in_sizes; (void)n_in; (void)out_size; (void)ws_size;

    const float* s0  = (const float*)d_in[0];
    const float* eps = (const float*)d_in[1];
    const float* Wih = (const float*)d_in[2];
    const float* Whh = (const float*)d_in[3];
    const float* bih = (const float*)d_in[4];
    const float* bhh = (const float*)d_in[5];
    const float* Wmu = (const float*)d_in[6];
    const float* bmu = (const float*)d_in[7];
    const float* Wlv = (const float*)d_in[8];
    const float* blv = (const float*)d_in[9];

    float* out = (float*)d_out;
    float* xs = out;                         // [1024][128]
    float* lp = out + TSTEPS * OUT_D;        // [1024][128]
    float* hs = out + 2 * TSTEPS * OUT_D;    // [1024][2048]

    unsigned int* flags = (unsigned int*)d_ws;   // 256 x 128B = 32KB

    // zero epoch flags each launch (graph replays re-run this memset)
    (void)hipMemsetAsync(d_ws, 0, NWG * FLAG_STRIDE * sizeof(unsigned int), stream);

    hipLaunchKernelGGL(lstm_persist, dim3(NWG), dim3(NTHR), 0, stream,
                       s0, Wih, Whh, bih, bhh, hs, flags);

    hipLaunchKernelGGL(out_head, dim3(TSTEPS / 4), dim3(256), 0, stream,
                       eps, Wmu, bmu, Wlv, blv, hs, xs, lp);
}

// Round 6
// 3620.467 us; speedup vs baseline: 22.1520x; 1.0699x over previous
//
#include <hip/hip_runtime.h>
#include <math.h>

#define TSTEPS 1024
#define HID    2048
#define IN_D   128
#define OUT_D  128
#define NWG    256
#define NTHR   512
#define NPAIRS (HID / 2)   // 1024 epoch-tagged 8B words per slot

#define LOG2PI_F 1.8378770664093453f

typedef unsigned long long u64;
typedef unsigned int       u32;

static __device__ __forceinline__ float sigmoidf_(float x) {
    return 1.0f / (1.0f + expf(-x));
}

// round-to-nearest-even f32 -> bf16 (returned in low 16 bits)
static __device__ __forceinline__ u32 bf16_rne(float f) {
    u32 u = __float_as_uint(f);
    return (u + 0x7FFFu + ((u >> 16) & 1u)) >> 16;
}
static __device__ __forceinline__ float bf16_lo(u32 payload) {   // bits 0..15
    return __uint_as_float(payload << 16);
}
static __device__ __forceinline__ float bf16_hi(u32 payload) {   // bits 16..31
    return __uint_as_float(payload & 0xFFFF0000u);
}

// ---------------------------------------------------------------------------
// Persistent LSTM rollout. 256 WGs x 512 threads; WG w owns h[8w..8w+8) and
// gate rows {g*2048 + 8w + i}. W_hh register-resident (128 f32/thread).
//
// Cross-WG h transport: epoch-tagged 8B words ("pairs"): low u32 = 2 x bf16
// (h[2p], h[2p+1]), high u32 = epoch tag (t+1 for step-t output). One relaxed
// agent-scope (L3-coherent) atomic store per pair IS both data and flag:
// - no separate flag store, no vmcnt serialization, no fences
// - consumer ordering is a pure data dependency (uses the polled word itself)
// - double buffer (slot = t&1) + tag check; data flow bounds skew < 2 steps
// Poll throttled with s_sleep(2); each thread polls only its own 2 pairs.
// ---------------------------------------------------------------------------
__global__ __launch_bounds__(NTHR, 2)
void lstm_persist(const float* __restrict__ s0,
                  const float* __restrict__ Wih,
                  const float* __restrict__ Whh,
                  const float* __restrict__ bih,
                  const float* __restrict__ bhh,
                  float* __restrict__ hs_out,
                  u64* __restrict__ pairs)     // [2][NPAIRS]
{
    __shared__ __align__(16) float4 ldsH[HID / 4];  // staged h(t-1), swizzled
    __shared__ __align__(16) float  gsum[32];

    const int tid   = threadIdx.x;
    const int wg    = blockIdx.x;
    const int hbase = wg * 8;
    const int rg    = tid >> 6;   // wave id 0..7
    const int lane  = tid & 63;

    // ---- W_hh -> registers: rows rg*4+m, k-slice [lane*32, lane*32+32) ----
    float w[4][32];
    int growm[4];
#pragma unroll
    for (int m = 0; m < 4; ++m) {
        const int li = rg * 4 + m;
        growm[m] = (li >> 3) * HID + hbase + (li & 7);
        const float4* src = (const float4*)(Whh + (size_t)growm[m] * HID + lane * 32);
#pragma unroll
        for (int q = 0; q < 8; ++q) {
            float4 v = src[q];
            w[m][4*q+0] = v.x; w[m][4*q+1] = v.y;
            w[m][4*q+2] = v.z; w[m][4*q+3] = v.w;
        }
    }
    // ---- W_ih -> registers: rows rg*4+m, k {2*lane, 2*lane+1}; fused bias ----
    float wih2[4][2];
    float breg[4];
#pragma unroll
    for (int m = 0; m < 4; ++m) {
        wih2[m][0] = Wih[(size_t)growm[m] * IN_D + 2 * lane];
        wih2[m][1] = Wih[(size_t)growm[m] * IN_D + 2 * lane + 1];
        breg[m]    = bih[growm[m]] + bhh[growm[m]];
    }

    float2 c2 = make_float2(0.f, 0.f);   // threads 0..3 own cells 2i, 2i+1

    for (int t = 0; t < TSTEPS; ++t) {
        // ---- W_ih @ x_t partial (no h dependency; L1-hot s0 row) ----
        const float2 xv = *(const float2*)(s0 + (size_t)t * IN_D + 2 * lane);
        float acc[4];
#pragma unroll
        for (int m = 0; m < 4; ++m)
            acc[m] = wih2[m][0] * xv.x + wih2[m][1] * xv.y;

        // ---- poll own 2 pairs of h(t-1); the polled words ARE the data ----
        if (t > 0) {
            const u32 want = (u32)t;
            const u64* sp = pairs + (size_t)((t - 1) & 1) * NPAIRS + 2 * tid;
            u64 q0, q1;
            for (;;) {
                q0 = __hip_atomic_load(sp,     __ATOMIC_RELAXED, __HIP_MEMORY_SCOPE_AGENT);
                q1 = __hip_atomic_load(sp + 1, __ATOMIC_RELAXED, __HIP_MEMORY_SCOPE_AGENT);
                if ((u32)(q0 >> 32) == want && (u32)(q1 >> 32) == want) break;
                __builtin_amdgcn_s_sleep(2);
            }
            float4 hv;
            hv.x = bf16_lo((u32)q0);
            hv.y = bf16_hi((u32)q0);
            hv.z = bf16_lo((u32)q1);
            hv.w = bf16_hi((u32)q1);
            const int p = tid ^ ((tid >> 3) & 7);   // 16B-chunk swizzle
            ldsH[p] = hv;
        }
        __syncthreads();   // sync1: ldsH staged

        // ---- recurrent matvec: 4 rows x 32 k per thread ----
        if (t > 0) {
#pragma unroll
            for (int j = 0; j < 8; ++j) {
                const int c4 = 8 * lane + j;
                const int p  = c4 ^ (lane & 7);
                float4 hv = ldsH[p];
#pragma unroll
                for (int m = 0; m < 4; ++m) {
                    acc[m] += hv.x * w[m][4*j+0];
                    acc[m] += hv.y * w[m][4*j+1];
                    acc[m] += hv.z * w[m][4*j+2];
                    acc[m] += hv.w * w[m][4*j+3];
                }
            }
        }

        // ---- full 64-lane butterfly; complete row sums land at lane 0 ----
#pragma unroll
        for (int m = 0; m < 4; ++m) {
            acc[m] += __shfl_xor(acc[m], 1);
            acc[m] += __shfl_xor(acc[m], 2);
            acc[m] += __shfl_xor(acc[m], 4);
            acc[m] += __shfl_xor(acc[m], 8);
            acc[m] += __shfl_xor(acc[m], 16);
            acc[m] += __shfl_xor(acc[m], 32);
        }
        if (lane == 0) {
            *(float4*)&gsum[rg * 4] = make_float4(acc[0] + breg[0], acc[1] + breg[1],
                                                  acc[2] + breg[2], acc[3] + breg[3]);
        }
        __syncthreads();   // sync2: gsum ready

        // ---- cell update + publish (threads 0..3, two cells each) ----
        if (tid < 4) {
            const int j0 = 2 * tid, j1 = 2 * tid + 1;
            const float i0 = sigmoidf_(gsum[j0]),      i1 = sigmoidf_(gsum[j1]);
            const float f0 = sigmoidf_(gsum[8  + j0]), f1 = sigmoidf_(gsum[8  + j1]);
            const float g0 = tanhf    (gsum[16 + j0]), g1 = tanhf    (gsum[16 + j1]);
            const float o0 = sigmoidf_(gsum[24 + j0]), o1 = sigmoidf_(gsum[24 + j1]);
            c2.x = f0 * c2.x + i0 * g0;
            c2.y = f1 * c2.y + i1 * g1;
            const float h0 = o0 * tanhf(c2.x);
            const float h1 = o1 * tanhf(c2.y);
            // publish FIRST: epoch-tagged bf16 pair -> L3 (data + flag in one)
            const u64 pkt = (u64)(bf16_rne(h0) | (bf16_rne(h1) << 16))
                          | ((u64)(u32)(t + 1) << 32);
            __hip_atomic_store(&pairs[(size_t)(t & 1) * NPAIRS + wg * 4 + tid], pkt,
                               __ATOMIC_RELAXED, __HIP_MEMORY_SCOPE_AGENT);
            // f32 record for the output head (plain store; flushed at kernel end)
            *(float2*)&hs_out[(size_t)t * HID + hbase + j0] = make_float2(h0, h1);
        }
        // no barrier: double buffer + epoch tags bound skew via data flow
    }
}

// ---------------------------------------------------------------------------
// Output head: mu/logvar GEMV + sample + logprob. Block = 4 timesteps,
// thread tid<128 -> mu row tid, tid>=128 -> lv row tid-128. hs is L2/L3-hot.
// ---------------------------------------------------------------------------
__global__ __launch_bounds__(256)
void out_head(const float* __restrict__ eps,
              const float* __restrict__ Wmu,
              const float* __restrict__ bmu,
              const float* __restrict__ Wlv,
              const float* __restrict__ blv,
              const float* __restrict__ hs,
              float* __restrict__ xs,
              float* __restrict__ lp)
{
    __shared__ __align__(16) float hlds[4][HID];
    __shared__ __align__(16) float exch[4][256];

    const int tid = threadIdx.x;
    const int t0  = blockIdx.x * 4;

    {
        const float4* src = (const float4*)(hs + (size_t)t0 * HID);
        float4* dst = (float4*)&hlds[0][0];
#pragma unroll
        for (int i = 0; i < 8; ++i)
            dst[tid + i * 256] = src[tid + i * 256];
    }
    __syncthreads();

    const int  jrow  = tid & 127;
    const bool is_lv = tid >= 128;
    const float* Wrow = (is_lv ? Wlv : Wmu) + (size_t)jrow * HID;
    const float  bias = is_lv ? blv[jrow] : bmu[jrow];

    float acc[4] = {0.f, 0.f, 0.f, 0.f};
    const float4* w4 = (const float4*)Wrow;
#pragma unroll 4
    for (int kq = 0; kq < HID / 4; ++kq) {
        float4 wv = w4[kq];
#pragma unroll
        for (int tt = 0; tt < 4; ++tt) {
            float4 hv = ((const float4*)&hlds[tt][0])[kq];
            acc[tt] += wv.x * hv.x + wv.y * hv.y + wv.z * hv.z + wv.w * hv.w;
        }
    }
#pragma unroll
    for (int tt = 0; tt < 4; ++tt) exch[tt][tid] = acc[tt] + bias;
    __syncthreads();

#pragma unroll
    for (int r = 0; r < 2; ++r) {
        const int item = tid + r * 256;
        const int tt = item >> 7;
        const int jj = item & 127;
        const int t  = t0 + tt;
        const float mu = exch[tt][jj];
        const float lv = exch[tt][128 + jj];
        const float e  = eps[(size_t)t * OUT_D + jj];
        const float sd = expf(0.5f * lv);
        const float x  = mu + sd * e;
        const float d  = (x - mu) / sd;
        const float l  = -0.5f * d * d - 0.5f * lv - 0.5f * LOG2PI_F;
        xs[(size_t)t * OUT_D + jj] = x;
        lp[(size_t)t * OUT_D + jj] = l;
    }
}

// ---------------------------------------------------------------------------
extern "C" void kernel_launch(void* const* d_in, const int* in_sizes, int n_in,
                              void* d_out, int out_size, void* d_ws, size_t ws_size,
                              hipStream_t stream)
{
    (void)in_sizes; (void)n_in; (void)out_size; (void)ws_size;

    const float* s0  = (const float*)d_in[0];
    const float* eps = (const float*)d_in[1];
    const float* Wih = (const float*)d_in[2];
    const float* Whh = (const float*)d_in[3];
    const float* bih = (const float*)d_in[4];
    const float* bhh = (const float*)d_in[5];
    const float* Wmu = (const float*)d_in[6];
    const float* bmu = (const float*)d_in[7];
    const float* Wlv = (const float*)d_in[8];
    const float* blv = (const float*)d_in[9];

    float* out = (float*)d_out;
    float* xs = out;                         // [1024][128]
    float* lp = out + TSTEPS * OUT_D;        // [1024][128]
    float* hs = out + 2 * TSTEPS * OUT_D;    // [1024][2048]

    u64* pairs = (u64*)d_ws;                 // [2][1024] x 8B = 16KB

    // zero tags each launch (epoch 0 matches no wanted tag >= 1)
    (void)hipMemsetAsync(d_ws, 0, 2 * NPAIRS * sizeof(u64), stream);

    hipLaunchKernelGGL(lstm_persist, dim3(NWG), dim3(NTHR), 0, stream,
                       s0, Wih, Whh, bih, bhh, hs, pairs);

    hipLaunchKernelGGL(out_head, dim3(TSTEPS / 4), dim3(256), 0, stream,
                       eps, Wmu, bmu, Wlv, blv, hs, xs, lp);
}